// Round 18
// baseline (421.566 us; speedup 1.0000x reference)
//
#include <hip/hip_runtime.h>
#include <hip/hip_bf16.h>
#include <stdint.h>

#define KDIM 4096
#define NDIM 4096
#define MDIM 4096
#define BM 256
#define BN 256
#define BK 64

typedef __attribute__((ext_vector_type(8))) short bf16x8;
typedef __attribute__((ext_vector_type(4))) float f32x4;

// ---------- helpers ----------

__device__ __forceinline__ unsigned short bf16bits(float f) {
    union { float f; uint32_t u; } c; c.f = f;
    uint32_t u = c.u;
    uint32_t r = (u + 0x7fffu + ((u >> 16) & 1u)) >> 16;   // RNE
    return (unsigned short)r;
}

// Faithful FP4 E2M1 quant-dequant (matches reference float math).
__device__ __forceinline__ float fp4qd(float x) {
    float a = fabsf(x);
    if (a == 0.0f) return 0.0f;
    float e = floorf(log2f(a));
    float val;
    if (e < 0.0f) {                       // subnormal path
        float mant = fminf(fmaxf(rintf(a * 2.0f), 0.0f), 1.0f);
        val = mant * 0.5f;
    } else {
        float ec = fminf(e, 2.0f);
        float p  = exp2f(ec);             // exact: 1,2,4
        float mant = fminf(fmaxf(rintf((a / p - 1.0f) * 2.0f), 0.0f), 1.0f);
        val = (1.0f + 0.5f * mant) * p;
    }
    return (x < 0.0f) ? -val : val;
}

__device__ __forceinline__ void gld16(void* lds, const void* g) {
    __builtin_amdgcn_global_load_lds(
        (const __attribute__((address_space(1))) unsigned int*)g,
        (__attribute__((address_space(3))) unsigned int*)lds,
        16, 0, 0);
}

// ---------- fused prep: x f32->bf16  +  weight fp4-quant-dequant->bf16 ----
__global__ __launch_bounds__(256) void prep_kernel(const float* __restrict__ X,
                                                   const float* __restrict__ W,
                                                   unsigned short* __restrict__ Xb,
                                                   unsigned short* __restrict__ Wq) {
    int bid = blockIdx.x;
    int tid = threadIdx.x;
    if (bid < 16384) {
        size_t i = ((size_t)bid * 256 + tid) * 4;
        float4 v = *(const float4*)(X + i);
        ushort4 o;
        o.x = bf16bits(v.x); o.y = bf16bits(v.y);
        o.z = bf16bits(v.z); o.w = bf16bits(v.w);
        *(ushort4*)(Xb + i) = o;
    } else {
        size_t base = ((size_t)(bid - 16384) * 256 + tid) * 4;
        float4 v = *(const float4*)(W + base);
        float am = fmaxf(fmaxf(fabsf(v.x), fabsf(v.y)),
                         fmaxf(fabsf(v.z), fabsf(v.w)));
        #pragma unroll
        for (int s = 16; s; s >>= 1) am = fmaxf(am, __shfl_xor(am, s));  // 32-lane group
        float scale = (am == 0.0f) ? 1.0f : am / 6.0f;
        ushort4 o;
        o.x = bf16bits(fp4qd(v.x / scale) * scale);
        o.y = bf16bits(fp4qd(v.y / scale) * scale);
        o.z = bf16bits(fp4qd(v.z / scale) * scale);
        o.w = bf16bits(fp4qd(v.w / scale) * scale);
        *(ushort4*)(Wq + base) = o;
    }
}

// ---------- GEMM: R17 + wave-parity MFMA cluster order ----------
// C = A @ B^T + bias. 8 waves (2M x 4N), per-wave 128x64, acc[8][4].
// LDS: smem[buf][op][half][16KB], 128 KiB dbuf. Chunk-XOR swizzle
// (slot = kc ^ (row&7)); conflict-free ds_read_b128.
// Memory ops / stages / barriers / vmcnt IDENTICAL to R11/R17.
// NEW: per phase, EVEN waves run the bvA-first cluster (first MFMA needs
// only av + pre-read bvA -> compiler waits lgkm(partial), starts early),
// ODD waves run bvB-first (lgkm(0), starts later). Staggered MFMA start
// times let late waves' LDS reads service UNDER early waves' MFMA
// (breaks the post-barrier all-wave read-burst lockstep). The swapped
// clusters touch DISJOINT acc elements -> numerics bit-identical.

#define BAR()    __builtin_amdgcn_s_barrier()
#define VM4()    asm volatile("s_waitcnt vmcnt(4)" ::: "memory")
#define SCH0()   __builtin_amdgcn_sched_barrier(0)
#define PRIO(x)  __builtin_amdgcn_s_setprio(x)

__global__ __launch_bounds__(512, 2) void gemm256(const unsigned short* __restrict__ A,
                                                  const unsigned short* __restrict__ B,
                                                  const float* __restrict__ bias,
                                                  float* __restrict__ C) {
    __shared__ __attribute__((aligned(16))) char smem[2][2][2][16384];
    char* sm = (char*)&smem[0][0][0][0];

    const int t = threadIdx.x;
    const int l = t & 63;
    const int w = __builtin_amdgcn_readfirstlane(t >> 6);  // 0..7
    const int wm = w >> 2;        // 0..1  (M half)
    const int wn = w & 3;         // 0..3  (N quarter)
    const bool wpar = (w & 1);    // wave parity (uniform)

    // bijective XCD swizzle (256 blocks, 8 XCDs)
    int bid = blockIdx.x;
    int swz = (bid & 7) * 32 + (bid >> 3);
    int brow = (swz >> 4) * BM;
    int bcol = (swz & 15) * BN;

    // ---- staging addresses (pre-swizzled global source, linear LDS dest) ----
    const int lr8  = l >> 3;
    const int slot = l & 7;
    const int scol = (slot ^ lr8) << 3;
    const unsigned short* pA = A + (size_t)(brow + w * 8 + lr8) * KDIM + scol;
    const unsigned short* pB = B + (size_t)(bcol + w * 8 + lr8) * KDIM + scol;

#define STAGE(b, op, h, kt) do {                                               \
    const unsigned short* _s = ((op) ? pB : pA)                                \
        + (size_t)(h) * 128 * KDIM + (size_t)(kt) * BK;                        \
    gld16(sm + (b) * 65536 + (op) * 32768 + (h) * 16384 + w * 1024, _s);       \
    gld16(sm + (b) * 65536 + (op) * 32768 + (h) * 16384 + 8192 + w * 1024,     \
          _s + (size_t)64 * KDIM);                                             \
} while (0)

    // ---- fragment read addressing ----
    const int fr  = l & 15;
    const int fq  = l >> 4;
    const int kx0 = ((fq    ) ^ (fr & 7)) << 4;
    const int kx1 = ((fq + 4) ^ (fr & 7)) << 4;
    const int frA = fr * 128;

#define RD_A(b, mh) do {                                                        \
    const char* _p = sm + (b) * 65536 + wm * 16384 + (mh) * 8192 + frA;         \
    _Pragma("unroll")                                                           \
    for (int m = 0; m < 4; ++m) {                                               \
        av[m][0] = *(const bf16x8*)(_p + m * 2048 + kx0);                       \
        av[m][1] = *(const bf16x8*)(_p + m * 2048 + kx1);                       \
    }                                                                           \
} while (0)

#define RD_B(b, nh, arr) do {                                                   \
    const char* _p = sm + (b) * 65536 + 32768 + wn * 8192 + (nh) * 4096 + frA;  \
    _Pragma("unroll")                                                           \
    for (int n = 0; n < 2; ++n) {                                               \
        arr[n][0] = *(const bf16x8*)(_p + n * 2048 + kx0);                      \
        arr[n][1] = *(const bf16x8*)(_p + n * 2048 + kx1);                      \
    }                                                                           \
} while (0)

// ks-outer: 8 independent MFMAs (distinct acc), then 8 (breaks dep pairs)
#define MM(mh, nh, B_)                                                          \
    _Pragma("unroll")                                                           \
    for (int ks = 0; ks < 2; ++ks)                                              \
        _Pragma("unroll")                                                       \
        for (int m = 0; m < 4; ++m)                                             \
            _Pragma("unroll")                                                   \
            for (int n = 0; n < 2; ++n)                                         \
                acc[(mh) * 4 + m][(nh) * 2 + n] =                               \
                    __builtin_amdgcn_mfma_f32_16x16x32_bf16(                    \
                        av[m][ks], B_[n][ks], acc[(mh) * 4 + m][(nh) * 2 + n],  \
                        0, 0, 0);

// parity-staggered pair of quadrant clusters (disjoint acc -> numerics same)
#define MMPAIR(mhA, nhA, BA_, mhB, nhB, BB_) do {                               \
    if (wpar) { PRIO(1); MM(mhB, nhB, BB_); MM(mhA, nhA, BA_); PRIO(0); }       \
    else      { PRIO(1); MM(mhA, nhA, BA_); MM(mhB, nhB, BB_); PRIO(0); }       \
} while (0)

    f32x4 acc[8][4];
    #pragma unroll
    for (int m = 0; m < 8; ++m)
        #pragma unroll
        for (int n = 0; n < 4; ++n)
            acc[m][n] = f32x4{0.f, 0.f, 0.f, 0.f};

    bf16x8 av[4][2], bvA[2][2], bvB[2][2];

    // ---- prologue: tile0 full (8 gld) + t1.B0 + t1.A0 (4 gld) ----
    STAGE(0, 0, 0, 0); STAGE(0, 0, 1, 0); STAGE(0, 1, 0, 0); STAGE(0, 1, 1, 0);
    STAGE(1, 1, 0, 1); STAGE(1, 0, 0, 1);
    VM4();            // tile0 landed; t1.B0/A0 in flight (4 ops)
    BAR(); SCH0();
    RD_B(0, 0, bvA);  // pre-read t0.B0 (consumed alpha & beta MM(·,0))

    // ---- main loop: 2 K-tiles / iteration, 2 barriers / K-tile ----
    for (int it = 0; it < 32; ++it) {
        const int k1 = 2 * it + 1;
        const int k2 = (2 * it + 2) & 63;   // wrap on last iter (never read)
        const int k3 = (2 * it + 3) & 63;

        // alpha-even: read buf0 A-mh0 (8) + B-nh1 (4) ; stage t1.A1, t1.B1
        RD_A(0, 0); RD_B(0, 1, bvB);
        STAGE(1, 0, 1, k1); STAGE(1, 1, 1, k1);
        BAR(); SCH0();
        MMPAIR(0, 0, bvA, 0, 1, bvB);
        // beta-even: read buf0 A-mh1 (8) ; stage t2.B0, t2.A0
        RD_A(0, 1);
        STAGE(0, 1, 0, k2); STAGE(0, 0, 0, k2);
        BAR(); SCH0();
        MMPAIR(1, 0, bvA, 1, 1, bvB);
        VM4(); RD_B(1, 0, bvA);   // buf1 (t1) fully landed; tail-read its B0

        // alpha-odd: read buf1 A-mh0 (8) + B-nh1 (4) ; stage t2.A1, t2.B1
        RD_A(1, 0); RD_B(1, 1, bvB);
        STAGE(0, 0, 1, k2); STAGE(0, 1, 1, k2);
        BAR(); SCH0();
        MMPAIR(0, 0, bvA, 0, 1, bvB);
        // beta-odd: read buf1 A-mh1 (8) ; stage t3.B0, t3.A0
        RD_A(1, 1);
        STAGE(1, 1, 0, k3); STAGE(1, 0, 0, k3);
        BAR(); SCH0();
        MMPAIR(1, 0, bvA, 1, 1, bvB);
        VM4(); RD_B(0, 0, bvA);   // buf0 (t2) fully landed; tail-read its B0
    }

    // ---- epilogue: C[row][col] = acc + bias[col] ----
    // C/D layout: col = lane&15, row = (lane>>4)*4 + reg
    float bb[4];
    #pragma unroll
    for (int n = 0; n < 4; ++n) bb[n] = bias[bcol + wn * 64 + n * 16 + fr];
    #pragma unroll
    for (int mi = 0; mi < 8; ++mi) {
        #pragma unroll
        for (int q = 0; q < 4; ++q) {
            int row = brow + wm * 128 + mi * 16 + fq * 4 + q;
            float* crow = C + (size_t)row * NDIM + bcol + wn * 64;
            #pragma unroll
            for (int n = 0; n < 4; ++n)
                crow[n * 16 + fr] = acc[mi][n][q] + bb[n];
        }
    }
}

// ---------- launch ----------
extern "C" void kernel_launch(void* const* d_in, const int* in_sizes, int n_in,
                              void* d_out, int out_size, void* d_ws, size_t ws_size,
                              hipStream_t stream) {
    const float* x = (const float*)d_in[0];
    const float* w = (const float*)d_in[1];
    const float* b = (const float*)d_in[2];
    float* out = (float*)d_out;

    unsigned short* xb = (unsigned short*)d_ws;                         // 32 MB
    unsigned short* wq = xb + (size_t)NDIM * KDIM;                      // 32 MB

    prep_kernel<<<32768, 256, 0, stream>>>(x, w, xb, wq);
    gemm256<<<(MDIM / BM) * (NDIM / BN), 512, 0, stream>>>(xb, wq, b, out);
}

// Round 19
// 147.400 us; speedup vs baseline: 2.8600x; 2.8600x over previous
//
#include <hip/hip_runtime.h>
#include <hip/hip_bf16.h>
#include <stdint.h>

#define KDIM 4096
#define NDIM 4096
#define MDIM 4096
#define BM 256
#define BN 256
#define BK 64

typedef __attribute__((ext_vector_type(8))) short bf16x8;
typedef __attribute__((ext_vector_type(4))) float f32x4;

// ---------- helpers ----------

__device__ __forceinline__ unsigned short bf16bits(float f) {
    union { float f; uint32_t u; } c; c.f = f;
    uint32_t u = c.u;
    uint32_t r = (u + 0x7fffu + ((u >> 16) & 1u)) >> 16;   // RNE
    return (unsigned short)r;
}

// Faithful FP4 E2M1 quant-dequant (matches reference float math).
__device__ __forceinline__ float fp4qd(float x) {
    float a = fabsf(x);
    if (a == 0.0f) return 0.0f;
    float e = floorf(log2f(a));
    float val;
    if (e < 0.0f) {                       // subnormal path
        float mant = fminf(fmaxf(rintf(a * 2.0f), 0.0f), 1.0f);
        val = mant * 0.5f;
    } else {
        float ec = fminf(e, 2.0f);
        float p  = exp2f(ec);             // exact: 1,2,4
        float mant = fminf(fmaxf(rintf((a / p - 1.0f) * 2.0f), 0.0f), 1.0f);
        val = (1.0f + 0.5f * mant) * p;
    }
    return (x < 0.0f) ? -val : val;
}

__device__ __forceinline__ void gld16(void* lds, const void* g) {
    __builtin_amdgcn_global_load_lds(
        (const __attribute__((address_space(1))) unsigned int*)g,
        (__attribute__((address_space(3))) unsigned int*)lds,
        16, 0, 0);
}

// ---------- fused prep: x f32->bf16  +  weight fp4-quant-dequant->bf16 ----
__global__ __launch_bounds__(256) void prep_kernel(const float* __restrict__ X,
                                                   const float* __restrict__ W,
                                                   unsigned short* __restrict__ Xb,
                                                   unsigned short* __restrict__ Wq) {
    int bid = blockIdx.x;
    int tid = threadIdx.x;
    if (bid < 16384) {
        size_t i = ((size_t)bid * 256 + tid) * 4;
        float4 v = *(const float4*)(X + i);
        ushort4 o;
        o.x = bf16bits(v.x); o.y = bf16bits(v.y);
        o.z = bf16bits(v.z); o.w = bf16bits(v.w);
        *(ushort4*)(Xb + i) = o;
    } else {
        size_t base = ((size_t)(bid - 16384) * 256 + tid) * 4;
        float4 v = *(const float4*)(W + base);
        float am = fmaxf(fmaxf(fabsf(v.x), fabsf(v.y)),
                         fmaxf(fabsf(v.z), fabsf(v.w)));
        #pragma unroll
        for (int s = 16; s; s >>= 1) am = fmaxf(am, __shfl_xor(am, s));  // 32-lane group
        float scale = (am == 0.0f) ? 1.0f : am / 6.0f;
        ushort4 o;
        o.x = bf16bits(fp4qd(v.x / scale) * scale);
        o.y = bf16bits(fp4qd(v.y / scale) * scale);
        o.z = bf16bits(fp4qd(v.z / scale) * scale);
        o.w = bf16bits(fp4qd(v.w / scale) * scale);
        *(ushort4*)(Wq + base) = o;
    }
}

// ---------- GEMM: R11 ledger, compiler-scheduled lgkm (R17, best) ----------
// C = A @ B^T + bias. 8 waves (2M x 4N), per-wave 128x64, acc[8][4].
// LDS: smem[buf][op][half][16KB], 128 KiB dbuf. Chunk-XOR swizzle
// (slot = kc ^ (row&7)); conflict-free ds_read_b128.
// 2 barriers / K-tile; counted vmcnt(4) at beta-end only; compiler emits
// fine-grained lgkmcnt between ds_read and consuming MFMA.
//  - RAW: VM4-counted drains + BAR precede reads of freshly staged buffers.
//  - WAR: each phase's reads are consumed by that phase's MFMAs before the
//    phase-end BAR that releases the overwriting stage.

#define BAR()    __builtin_amdgcn_s_barrier()
#define VM4()    asm volatile("s_waitcnt vmcnt(4)" ::: "memory")
#define SCH0()   __builtin_amdgcn_sched_barrier(0)
#define PRIO(x)  __builtin_amdgcn_s_setprio(x)

__global__ __launch_bounds__(512, 2) void gemm256(const unsigned short* __restrict__ A,
                                                  const unsigned short* __restrict__ B,
                                                  const float* __restrict__ bias,
                                                  float* __restrict__ C) {
    __shared__ __attribute__((aligned(16))) char smem[2][2][2][16384];
    char* sm = (char*)&smem[0][0][0][0];

    const int t = threadIdx.x;
    const int l = t & 63;
    const int w = __builtin_amdgcn_readfirstlane(t >> 6);  // 0..7
    const int wm = w >> 2;        // 0..1  (M half)
    const int wn = w & 3;         // 0..3  (N quarter)

    // bijective XCD swizzle (256 blocks, 8 XCDs)
    int bid = blockIdx.x;
    int swz = (bid & 7) * 32 + (bid >> 3);
    int brow = (swz >> 4) * BM;
    int bcol = (swz & 15) * BN;

    // ---- staging addresses (pre-swizzled global source, linear LDS dest) ----
    const int lr8  = l >> 3;
    const int slot = l & 7;
    const int scol = (slot ^ lr8) << 3;
    const unsigned short* pA = A + (size_t)(brow + w * 8 + lr8) * KDIM + scol;
    const unsigned short* pB = B + (size_t)(bcol + w * 8 + lr8) * KDIM + scol;

#define STAGE(b, op, h, kt) do {                                               \
    const unsigned short* _s = ((op) ? pB : pA)                                \
        + (size_t)(h) * 128 * KDIM + (size_t)(kt) * BK;                        \
    gld16(sm + (b) * 65536 + (op) * 32768 + (h) * 16384 + w * 1024, _s);       \
    gld16(sm + (b) * 65536 + (op) * 32768 + (h) * 16384 + 8192 + w * 1024,     \
          _s + (size_t)64 * KDIM);                                             \
} while (0)

    // ---- fragment read addressing ----
    const int fr  = l & 15;
    const int fq  = l >> 4;
    const int kx0 = ((fq    ) ^ (fr & 7)) << 4;
    const int kx1 = ((fq + 4) ^ (fr & 7)) << 4;
    const int frA = fr * 128;

#define RD_A(b, mh) do {                                                        \
    const char* _p = sm + (b) * 65536 + wm * 16384 + (mh) * 8192 + frA;         \
    _Pragma("unroll")                                                           \
    for (int m = 0; m < 4; ++m) {                                               \
        av[m][0] = *(const bf16x8*)(_p + m * 2048 + kx0);                       \
        av[m][1] = *(const bf16x8*)(_p + m * 2048 + kx1);                       \
    }                                                                           \
} while (0)

#define RD_B(b, nh, arr) do {                                                   \
    const char* _p = sm + (b) * 65536 + 32768 + wn * 8192 + (nh) * 4096 + frA;  \
    _Pragma("unroll")                                                           \
    for (int n = 0; n < 2; ++n) {                                               \
        arr[n][0] = *(const bf16x8*)(_p + n * 2048 + kx0);                      \
        arr[n][1] = *(const bf16x8*)(_p + n * 2048 + kx1);                      \
    }                                                                           \
} while (0)

// ks-outer: 8 independent MFMAs (distinct acc), then 8 (breaks dep pairs)
#define MM(mh, nh, B_)                                                          \
    _Pragma("unroll")                                                           \
    for (int ks = 0; ks < 2; ++ks)                                              \
        _Pragma("unroll")                                                       \
        for (int m = 0; m < 4; ++m)                                             \
            _Pragma("unroll")                                                   \
            for (int n = 0; n < 2; ++n)                                         \
                acc[(mh) * 4 + m][(nh) * 2 + n] =                               \
                    __builtin_amdgcn_mfma_f32_16x16x32_bf16(                    \
                        av[m][ks], B_[n][ks], acc[(mh) * 4 + m][(nh) * 2 + n],  \
                        0, 0, 0);

    f32x4 acc[8][4];
    #pragma unroll
    for (int m = 0; m < 8; ++m)
        #pragma unroll
        for (int n = 0; n < 4; ++n)
            acc[m][n] = f32x4{0.f, 0.f, 0.f, 0.f};

    bf16x8 av[4][2], bvA[2][2], bvB[2][2];

    // ---- prologue: tile0 full (8 gld) + t1.B0 + t1.A0 (4 gld) ----
    STAGE(0, 0, 0, 0); STAGE(0, 0, 1, 0); STAGE(0, 1, 0, 0); STAGE(0, 1, 1, 0);
    STAGE(1, 1, 0, 1); STAGE(1, 0, 0, 1);
    VM4();            // tile0 landed; t1.B0/A0 in flight (4 ops)
    BAR(); SCH0();
    RD_B(0, 0, bvA);  // pre-read t0.B0 (consumed alpha & beta MM(·,0))

    // ---- main loop: 2 K-tiles / iteration, 2 barriers / K-tile ----
    for (int it = 0; it < 32; ++it) {
        const int k1 = 2 * it + 1;
        const int k2 = (2 * it + 2) & 63;   // wrap on last iter (never read)
        const int k3 = (2 * it + 3) & 63;

        // alpha-even: read buf0 A-mh0 (8) + B-nh1 (4) ; stage t1.A1, t1.B1
        RD_A(0, 0); RD_B(0, 1, bvB);
        STAGE(1, 0, 1, k1); STAGE(1, 1, 1, k1);
        BAR(); SCH0();
        PRIO(1); MM(0, 0, bvA); MM(0, 1, bvB); PRIO(0);
        // beta-even: read buf0 A-mh1 (8) ; stage t2.B0, t2.A0
        RD_A(0, 1);
        STAGE(0, 1, 0, k2); STAGE(0, 0, 0, k2);
        BAR(); SCH0();
        PRIO(1); MM(1, 1, bvB); MM(1, 0, bvA); PRIO(0);
        VM4(); RD_B(1, 0, bvA);   // buf1 (t1) fully landed; tail-read its B0

        // alpha-odd: read buf1 A-mh0 (8) + B-nh1 (4) ; stage t2.A1, t2.B1
        RD_A(1, 0); RD_B(1, 1, bvB);
        STAGE(0, 0, 1, k2); STAGE(0, 1, 1, k2);
        BAR(); SCH0();
        PRIO(1); MM(0, 0, bvA); MM(0, 1, bvB); PRIO(0);
        // beta-odd: read buf1 A-mh1 (8) ; stage t3.B0, t3.A0
        RD_A(1, 1);
        STAGE(1, 1, 0, k3); STAGE(1, 0, 0, k3);
        BAR(); SCH0();
        PRIO(1); MM(1, 1, bvB); MM(1, 0, bvA); PRIO(0);
        VM4(); RD_B(0, 0, bvA);   // buf0 (t2) fully landed; tail-read its B0
    }

    // ---- epilogue: C[row][col] = acc + bias[col] ----
    // C/D layout: col = lane&15, row = (lane>>4)*4 + reg
    float bb[4];
    #pragma unroll
    for (int n = 0; n < 4; ++n) bb[n] = bias[bcol + wn * 64 + n * 16 + fr];
    #pragma unroll
    for (int mi = 0; mi < 8; ++mi) {
        #pragma unroll
        for (int q = 0; q < 4; ++q) {
            int row = brow + wm * 128 + mi * 16 + fq * 4 + q;
            float* crow = C + (size_t)row * NDIM + bcol + wn * 64;
            #pragma unroll
            for (int n = 0; n < 4; ++n)
                crow[n * 16 + fr] = acc[mi][n][q] + bb[n];
        }
    }
}

// ---------- launch ----------
extern "C" void kernel_launch(void* const* d_in, const int* in_sizes, int n_in,
                              void* d_out, int out_size, void* d_ws, size_t ws_size,
                              hipStream_t stream) {
    const float* x = (const float*)d_in[0];
    const float* w = (const float*)d_in[1];
    const float* b = (const float*)d_in[2];
    float* out = (float*)d_out;

    unsigned short* xb = (unsigned short*)d_ws;                         // 32 MB
    unsigned short* wq = xb + (size_t)NDIM * KDIM;                      // 32 MB

    prep_kernel<<<32768, 256, 0, stream>>>(x, w, xb, wq);
    gemm256<<<(MDIM / BM) * (NDIM / BN), 512, 0, stream>>>(xb, wq, b, out);
}

// Round 20
// 137.644 us; speedup vs baseline: 3.0627x; 1.0709x over previous
//
#include <hip/hip_runtime.h>
#include <hip/hip_bf16.h>
#include <stdint.h>

#define KDIM 4096
#define NDIM 4096
#define MDIM 4096
#define BM 256
#define BN 256
#define BK 64

typedef __attribute__((ext_vector_type(8))) short bf16x8;
typedef __attribute__((ext_vector_type(4))) float f32x4;

// ---------- helpers ----------

__device__ __forceinline__ unsigned short bf16bits(float f) {
    union { float f; uint32_t u; } c; c.f = f;
    uint32_t u = c.u;
    uint32_t r = (u + 0x7fffu + ((u >> 16) & 1u)) >> 16;   // RNE
    return (unsigned short)r;
}

// ---------- fused prep: x f32->bf16  +  weight fp4-quant-dequant->bf16 ----
// wdeq: branchless threshold form of the reference E2M1 quant-dequant.
// The reference maps |y| (y = w/scale) onto {0,.5,1,1.5,2,3,4,6} with
// boundaries {.25,1,1.25,2,2.5,4,5}; rintf ties-to-even makes ties at
// .25/1.25/2.5/5 round DOWN (strict >) and 1/2/4 are closed below (>=).
// Thresholds are pre-multiplied by scale, eliminating the per-element
// correctly-rounded division + log2f/exp2f/rintf chain (~34 -> ~22 ops).
__global__ __launch_bounds__(256) void prep_kernel(const float* __restrict__ X,
                                                   const float* __restrict__ W,
                                                   unsigned short* __restrict__ Xb,
                                                   unsigned short* __restrict__ Wq) {
    int bid = blockIdx.x;
    int tid = threadIdx.x;
    if (bid < 16384) {
        size_t i = ((size_t)bid * 256 + tid) * 4;
        float4 v = *(const float4*)(X + i);
        ushort4 o;
        o.x = bf16bits(v.x); o.y = bf16bits(v.y);
        o.z = bf16bits(v.z); o.w = bf16bits(v.w);
        *(ushort4*)(Xb + i) = o;
    } else {
        size_t base = ((size_t)(bid - 16384) * 256 + tid) * 4;
        float4 v = *(const float4*)(W + base);
        float am = fmaxf(fmaxf(fabsf(v.x), fabsf(v.y)),
                         fmaxf(fabsf(v.z), fabsf(v.w)));
        #pragma unroll
        for (int s = 16; s; s >>= 1) am = fmaxf(am, __shfl_xor(am, s));  // 32-lane group
        float scale = (am == 0.0f) ? 1.0f : am / 6.0f;

        const float t0 = 0.25f * scale, t1 = 1.0f * scale, t2 = 1.25f * scale,
                    t3 = 2.0f  * scale, t4 = 2.5f * scale, t5 = 4.0f  * scale,
                    t6 = 5.0f  * scale;

        float in[4] = { v.x, v.y, v.z, v.w };
        unsigned short ob[4];
        #pragma unroll
        for (int j = 0; j < 4; ++j) {
            float a = fabsf(in[j]);
            float q = 0.0f;
            q += (a >  t0) ? 0.5f : 0.0f;
            q += (a >= t1) ? 0.5f : 0.0f;
            q += (a >  t2) ? 0.5f : 0.0f;
            q += (a >= t3) ? 0.5f : 0.0f;
            q += (a >  t4) ? 1.0f : 0.0f;
            q += (a >= t5) ? 1.0f : 0.0f;
            q += (a >  t6) ? 2.0f : 0.0f;
            float wv = q * scale;
            wv = (in[j] < 0.0f) ? -wv : wv;
            ob[j] = bf16bits(wv);
        }
        ushort4 o;
        o.x = ob[0]; o.y = ob[1]; o.z = ob[2]; o.w = ob[3];
        *(ushort4*)(Wq + base) = o;
    }
}

// ---------- GEMM: R11 ledger, compiler-scheduled lgkm (R17, best) ----------
// C = A @ B^T + bias. 8 waves (2M x 4N), per-wave 128x64, acc[8][4].
// LDS: smem[buf][op][half][16KB], 128 KiB dbuf. Chunk-XOR swizzle
// (slot = kc ^ (row&7)); conflict-free ds_read_b128.
// 2 barriers / K-tile; counted vmcnt(4) at beta-end only; compiler emits
// fine-grained lgkmcnt between ds_read and consuming MFMA.
//  - RAW: VM4-counted drains + BAR precede reads of freshly staged buffers.
//  - WAR: each phase's reads are consumed by that phase's MFMAs before the
//    phase-end BAR that releases the overwriting stage.

#define BAR()    __builtin_amdgcn_s_barrier()
#define VM4()    asm volatile("s_waitcnt vmcnt(4)" ::: "memory")
#define SCH0()   __builtin_amdgcn_sched_barrier(0)
#define PRIO(x)  __builtin_amdgcn_s_setprio(x)

__device__ __forceinline__ void gld16(void* lds, const void* g) {
    __builtin_amdgcn_global_load_lds(
        (const __attribute__((address_space(1))) unsigned int*)g,
        (__attribute__((address_space(3))) unsigned int*)lds,
        16, 0, 0);
}

__global__ __launch_bounds__(512, 2) void gemm256(const unsigned short* __restrict__ A,
                                                  const unsigned short* __restrict__ B,
                                                  const float* __restrict__ bias,
                                                  float* __restrict__ C) {
    __shared__ __attribute__((aligned(16))) char smem[2][2][2][16384];
    char* sm = (char*)&smem[0][0][0][0];

    const int t = threadIdx.x;
    const int l = t & 63;
    const int w = __builtin_amdgcn_readfirstlane(t >> 6);  // 0..7
    const int wm = w >> 2;        // 0..1  (M half)
    const int wn = w & 3;         // 0..3  (N quarter)

    // bijective XCD swizzle (256 blocks, 8 XCDs)
    int bid = blockIdx.x;
    int swz = (bid & 7) * 32 + (bid >> 3);
    int brow = (swz >> 4) * BM;
    int bcol = (swz & 15) * BN;

    // ---- staging addresses (pre-swizzled global source, linear LDS dest) ----
    const int lr8  = l >> 3;
    const int slot = l & 7;
    const int scol = (slot ^ lr8) << 3;
    const unsigned short* pA = A + (size_t)(brow + w * 8 + lr8) * KDIM + scol;
    const unsigned short* pB = B + (size_t)(bcol + w * 8 + lr8) * KDIM + scol;

#define STAGE(b, op, h, kt) do {                                               \
    const unsigned short* _s = ((op) ? pB : pA)                                \
        + (size_t)(h) * 128 * KDIM + (size_t)(kt) * BK;                        \
    gld16(sm + (b) * 65536 + (op) * 32768 + (h) * 16384 + w * 1024, _s);       \
    gld16(sm + (b) * 65536 + (op) * 32768 + (h) * 16384 + 8192 + w * 1024,     \
          _s + (size_t)64 * KDIM);                                             \
} while (0)

    // ---- fragment read addressing ----
    const int fr  = l & 15;
    const int fq  = l >> 4;
    const int kx0 = ((fq    ) ^ (fr & 7)) << 4;
    const int kx1 = ((fq + 4) ^ (fr & 7)) << 4;
    const int frA = fr * 128;

#define RD_A(b, mh) do {                                                        \
    const char* _p = sm + (b) * 65536 + wm * 16384 + (mh) * 8192 + frA;         \
    _Pragma("unroll")                                                           \
    for (int m = 0; m < 4; ++m) {                                               \
        av[m][0] = *(const bf16x8*)(_p + m * 2048 + kx0);                       \
        av[m][1] = *(const bf16x8*)(_p + m * 2048 + kx1);                       \
    }                                                                           \
} while (0)

#define RD_B(b, nh, arr) do {                                                   \
    const char* _p = sm + (b) * 65536 + 32768 + wn * 8192 + (nh) * 4096 + frA;  \
    _Pragma("unroll")                                                           \
    for (int n = 0; n < 2; ++n) {                                               \
        arr[n][0] = *(const bf16x8*)(_p + n * 2048 + kx0);                      \
        arr[n][1] = *(const bf16x8*)(_p + n * 2048 + kx1);                      \
    }                                                                           \
} while (0)

// ks-outer: 8 independent MFMAs (distinct acc), then 8 (breaks dep pairs)
#define MM(mh, nh, B_)                                                          \
    _Pragma("unroll")                                                           \
    for (int ks = 0; ks < 2; ++ks)                                              \
        _Pragma("unroll")                                                       \
        for (int m = 0; m < 4; ++m)                                             \
            _Pragma("unroll")                                                   \
            for (int n = 0; n < 2; ++n)                                         \
                acc[(mh) * 4 + m][(nh) * 2 + n] =                               \
                    __builtin_amdgcn_mfma_f32_16x16x32_bf16(                    \
                        av[m][ks], B_[n][ks], acc[(mh) * 4 + m][(nh) * 2 + n],  \
                        0, 0, 0);

    f32x4 acc[8][4];
    #pragma unroll
    for (int m = 0; m < 8; ++m)
        #pragma unroll
        for (int n = 0; n < 4; ++n)
            acc[m][n] = f32x4{0.f, 0.f, 0.f, 0.f};

    bf16x8 av[4][2], bvA[2][2], bvB[2][2];

    // ---- prologue: tile0 full (8 gld) + t1.B0 + t1.A0 (4 gld) ----
    STAGE(0, 0, 0, 0); STAGE(0, 0, 1, 0); STAGE(0, 1, 0, 0); STAGE(0, 1, 1, 0);
    STAGE(1, 1, 0, 1); STAGE(1, 0, 0, 1);
    VM4();            // tile0 landed; t1.B0/A0 in flight (4 ops)
    BAR(); SCH0();
    RD_B(0, 0, bvA);  // pre-read t0.B0 (consumed alpha & beta MM(·,0))

    // ---- main loop: 2 K-tiles / iteration, 2 barriers / K-tile ----
    for (int it = 0; it < 32; ++it) {
        const int k1 = 2 * it + 1;
        const int k2 = (2 * it + 2) & 63;   // wrap on last iter (never read)
        const int k3 = (2 * it + 3) & 63;

        // alpha-even: read buf0 A-mh0 (8) + B-nh1 (4) ; stage t1.A1, t1.B1
        RD_A(0, 0); RD_B(0, 1, bvB);
        STAGE(1, 0, 1, k1); STAGE(1, 1, 1, k1);
        BAR(); SCH0();
        PRIO(1); MM(0, 0, bvA); MM(0, 1, bvB); PRIO(0);
        // beta-even: read buf0 A-mh1 (8) ; stage t2.B0, t2.A0
        RD_A(0, 1);
        STAGE(0, 1, 0, k2); STAGE(0, 0, 0, k2);
        BAR(); SCH0();
        PRIO(1); MM(1, 1, bvB); MM(1, 0, bvA); PRIO(0);
        VM4(); RD_B(1, 0, bvA);   // buf1 (t1) fully landed; tail-read its B0

        // alpha-odd: read buf1 A-mh0 (8) + B-nh1 (4) ; stage t2.A1, t2.B1
        RD_A(1, 0); RD_B(1, 1, bvB);
        STAGE(0, 0, 1, k2); STAGE(0, 1, 1, k2);
        BAR(); SCH0();
        PRIO(1); MM(0, 0, bvA); MM(0, 1, bvB); PRIO(0);
        // beta-odd: read buf1 A-mh1 (8) ; stage t3.B0, t3.A0
        RD_A(1, 1);
        STAGE(1, 1, 0, k3); STAGE(1, 0, 0, k3);
        BAR(); SCH0();
        PRIO(1); MM(1, 1, bvB); MM(1, 0, bvA); PRIO(0);
        VM4(); RD_B(0, 0, bvA);   // buf0 (t2) fully landed; tail-read its B0
    }

    // ---- epilogue: C[row][col] = acc + bias[col] ----
    // C/D layout: col = lane&15, row = (lane>>4)*4 + reg
    float bb[4];
    #pragma unroll
    for (int n = 0; n < 4; ++n) bb[n] = bias[bcol + wn * 64 + n * 16 + fr];
    #pragma unroll
    for (int mi = 0; mi < 8; ++mi) {
        #pragma unroll
        for (int q = 0; q < 4; ++q) {
            int row = brow + wm * 128 + mi * 16 + fq * 4 + q;
            float* crow = C + (size_t)row * NDIM + bcol + wn * 64;
            #pragma unroll
            for (int n = 0; n < 4; ++n)
                crow[n * 16 + fr] = acc[mi][n][q] + bb[n];
        }
    }
}

// ---------- launch ----------
extern "C" void kernel_launch(void* const* d_in, const int* in_sizes, int n_in,
                              void* d_out, int out_size, void* d_ws, size_t ws_size,
                              hipStream_t stream) {
    const float* x = (const float*)d_in[0];
    const float* w = (const float*)d_in[1];
    const float* b = (const float*)d_in[2];
    float* out = (float*)d_out;

    unsigned short* xb = (unsigned short*)d_ws;                         // 32 MB
    unsigned short* wq = xb + (size_t)NDIM * KDIM;                      // 32 MB

    prep_kernel<<<32768, 256, 0, stream>>>(x, w, xb, wq);
    gemm256<<<(MDIM / BM) * (NDIM / BN), 512, 0, stream>>>(xb, wq, b, out);
}